// Round 1
// baseline (3625.179 us; speedup 1.0000x reference)
//
#include <hip/hip_runtime.h>

// Problem constants (from reference)
#define NB 16      // batch
#define SS 7500    // sequence
#define HH 64      // hidden
#define TT 300     // frames (attention length)
#define NHEAD 4    // heads
#define DKV 64     // att size per head
#define NJ 25      // joint groups = S / T
#define HD 256     // NHEAD * DKV

// One block per (b, j, h). 320 threads = 5 waves.
// LDS: K' and V' tiles (300x64 fp32 each) = 153.6 KB (fits gfx950 160KB/WG).
__global__ __launch_bounds__(320, 1)
void mha_fused(const float* __restrict__ q, const float* __restrict__ k,
               const float* __restrict__ v,
               const float* __restrict__ Wq, const float* __restrict__ Wk,
               const float* __restrict__ Wv, const float* __restrict__ Wo,
               float* __restrict__ out)
{
    __shared__ float sK[TT * DKV];   // 76.8 KB
    __shared__ float sV[TT * DKV];   // 76.8 KB

    const int blk = blockIdx.x;          // 0..1599
    const int h   = blk & (NHEAD - 1);   // head
    const int bj  = blk >> 2;            // 0..399
    const int j   = bj % NJ;
    const int b   = bj / NJ;

    const int tid    = threadIdx.x;
    const int lane_d = tid & 63;         // output column within head slice
    const int trow   = tid >> 6;         // wave id 0..4

    const long xbase = ((long)b * SS + (long)j * TT) * HH;  // first row of this (b,j) group

    // ---- Projection phase: K' and V' into LDS ----
    // wave `trow` handles rows t = trow, trow+5, ... ; lane handles column lane_d.
    {
        float wcol[HH];
        #pragma unroll
        for (int i = 0; i < HH; ++i)
            wcol[i] = Wk[i * HD + h * DKV + lane_d];
        for (int t = trow; t < TT; t += 5) {
            const float* xr = k + xbase + (long)t * HH;   // wave-uniform row -> broadcast loads
            float a0 = 0.f, a1 = 0.f, a2 = 0.f, a3 = 0.f;
            #pragma unroll
            for (int i = 0; i < HH; i += 4) {
                a0 = fmaf(xr[i],     wcol[i],     a0);
                a1 = fmaf(xr[i + 1], wcol[i + 1], a1);
                a2 = fmaf(xr[i + 2], wcol[i + 2], a2);
                a3 = fmaf(xr[i + 3], wcol[i + 3], a3);
            }
            sK[t * DKV + lane_d] = (a0 + a1) + (a2 + a3);
        }
        #pragma unroll
        for (int i = 0; i < HH; ++i)
            wcol[i] = Wv[i * HD + h * DKV + lane_d];
        for (int t = trow; t < TT; t += 5) {
            const float* xr = v + xbase + (long)t * HH;
            float a0 = 0.f, a1 = 0.f, a2 = 0.f, a3 = 0.f;
            #pragma unroll
            for (int i = 0; i < HH; i += 4) {
                a0 = fmaf(xr[i],     wcol[i],     a0);
                a1 = fmaf(xr[i + 1], wcol[i + 1], a1);
                a2 = fmaf(xr[i + 2], wcol[i + 2], a2);
                a3 = fmaf(xr[i + 3], wcol[i + 3], a3);
            }
            sV[t * DKV + lane_d] = (a0 + a1) + (a2 + a3);
        }
    }
    __syncthreads();

    // ---- Attention phase: one thread per query frame t ----
    if (tid < TT) {
        const int t = tid;

        // Q' row for this query (recomputed per thread; Wq rows are lane-uniform -> broadcast)
        float qreg[DKV];
        #pragma unroll
        for (int d = 0; d < DKV; ++d) qreg[d] = 0.f;
        {
            const float* xr = q + xbase + (long)t * HH;
            float x[HH];
            #pragma unroll
            for (int i = 0; i < HH; i += 4) {
                const float4 xv = *(const float4*)(xr + i);
                x[i] = xv.x; x[i + 1] = xv.y; x[i + 2] = xv.z; x[i + 3] = xv.w;
            }
            for (int i = 0; i < HH; ++i) {
                const float xi = x[i];
                const float* wr = Wq + i * HD + h * DKV;
                #pragma unroll
                for (int d = 0; d < DKV; ++d)
                    qreg[d] = fmaf(xi, wr[d], qreg[d]);
            }
        }
        #pragma unroll
        for (int d = 0; d < DKV; ++d) qreg[d] *= 0.125f;   // dk^-0.5

        // Online softmax over s = 0..299, K'/V' rows broadcast from LDS
        float m = -3.0e38f, l = 0.f;
        float acc[DKV];
        #pragma unroll
        for (int d = 0; d < DKV; ++d) acc[d] = 0.f;

        for (int s = 0; s < TT; ++s) {
            const float* kr = &sK[s * DKV];
            float d0 = 0.f, d1 = 0.f, d2 = 0.f, d3 = 0.f;
            #pragma unroll
            for (int d = 0; d < DKV; d += 4) {
                d0 = fmaf(qreg[d],     kr[d],     d0);
                d1 = fmaf(qreg[d + 1], kr[d + 1], d1);
                d2 = fmaf(qreg[d + 2], kr[d + 2], d2);
                d3 = fmaf(qreg[d + 3], kr[d + 3], d3);
            }
            const float dot  = (d0 + d1) + (d2 + d3);
            const float mnew = fmaxf(m, dot);
            const float corr = __expf(m - mnew);     // 0 on first iter (underflow)
            const float p    = __expf(dot - mnew);
            l = l * corr + p;
            const float* vr = &sV[s * DKV];
            #pragma unroll
            for (int d = 0; d < DKV; ++d)
                acc[d] = fmaf(p, vr[d], acc[d] * corr);
            m = mnew;
        }
        const float inv = 1.f / l;

        // Fused output projection: o = (acc/l) @ Wo[h*64 .. h*64+63, :]
        float o[HH];
        #pragma unroll
        for (int c = 0; c < HH; ++c) o[c] = 0.f;
        for (int d = 0; d < DKV; ++d) {
            const float a = acc[d] * inv;
            const float* wr = Wo + (long)(h * DKV + d) * HH;
            #pragma unroll
            for (int c = 0; c < HH; ++c)
                o[c] = fmaf(a, wr[c], o[c]);
        }
        float* orow = out + xbase + (long)t * HH;
        #pragma unroll
        for (int c = 0; c < HH; ++c)
            atomicAdd(orow + c, o[c]);   // 4-way contention (one per head)
    }
}

extern "C" void kernel_launch(void* const* d_in, const int* in_sizes, int n_in,
                              void* d_out, int out_size, void* d_ws, size_t ws_size,
                              hipStream_t stream) {
    const float* q  = (const float*)d_in[0];
    const float* k  = (const float*)d_in[1];
    const float* v  = (const float*)d_in[2];
    const float* Wq = (const float*)d_in[3];
    const float* Wk = (const float*)d_in[4];
    const float* Wv = (const float*)d_in[5];
    const float* Wo = (const float*)d_in[6];
    float* out = (float*)d_out;

    // Output is accumulated via atomics across the 4 heads -> must start at zero.
    // hipMemsetAsync is graph-capture-safe.
    hipMemsetAsync(out, 0, (size_t)out_size * sizeof(float), stream);

    const dim3 grid(NB * NJ * NHEAD);   // 1600 blocks, one per (b, j, h)
    mha_fused<<<grid, 320, 0, stream>>>(q, k, v, Wq, Wk, Wv, Wo, out);
}

// Round 2
// 463.208 us; speedup vs baseline: 7.8262x; 7.8262x over previous
//
#include <hip/hip_runtime.h>

// Problem constants
#define NB 16
#define SS 7500
#define HH 64      // hidden (= input dim of projections, = output dim)
#define TT 300     // frames per joint group
#define NHEAD 4
#define DKV 64     // per-head att size
#define NJ 25      // S / T
#define HDW 256    // NHEAD*DKV
#define TPAD 320   // T padded to 10 s-tiles of 32
#define NQT 19     // ceil(300/16) q-tiles
#define NST 10     // s-tiles of 32
#define KSTR 72    // sK / scratch row stride (bf16 elems), 72%8==0 for b128 align
#define VSTR 328   // sVT row stride
#define WSTR 72
#define NWAVE 8
#define MAXTILE 3

typedef __attribute__((ext_vector_type(8))) short short8;  // 8 bf16
typedef __attribute__((ext_vector_type(4))) float f32x4;

__device__ inline short f2bf(float f) {  // fp32 -> bf16 RNE
    union { float f; unsigned u; } x; x.f = f;
    unsigned u = x.u + 0x7FFFu + ((x.u >> 16) & 1u);
    return (short)(u >> 16);
}

#define MFMA(a, b, c) __builtin_amdgcn_mfma_f32_16x16x32_bf16((a), (b), (c), 0, 0, 0)
#define LGKM_BAR() asm volatile("s_waitcnt lgkmcnt(0)" ::: "memory")

// One block per (b, j). 512 threads = 8 waves. Heads processed sequentially,
// output accumulated in MFMA C-frags in registers -> plain stores (no atomics).
__global__ __launch_bounds__(512, 1)
void mha_mfma(const float* __restrict__ q, const float* __restrict__ k,
              const float* __restrict__ v,
              const float* __restrict__ Wq, const float* __restrict__ Wk,
              const float* __restrict__ Wv, const float* __restrict__ Wo,
              float* __restrict__ out)
{
    __shared__ short sK [TPAD * KSTR];   // K' row-major [s][d]      46080 B
    __shared__ short sVT[DKV * VSTR];    // V' transposed [d][s]     41984 B
    __shared__ short sWq[DKV * WSTR];    // W^T head slice [out][in]  9216 B
    __shared__ short sWk[DKV * WSTR];
    __shared__ short sWv[DKV * WSTR];
    __shared__ short sWo[DKV * WSTR];    // [out_col][dkv]
    __shared__ short sScr[NWAVE][16 * KSTR];  // per-wave C->A round-trip  18432 B

    const int tid  = threadIdx.x;
    const int w    = tid >> 6;
    const int lane = tid & 63;
    const int L15  = lane & 15;
    const int quad = lane >> 4;

    const int blk = blockIdx.x;      // 0..399
    const int j = blk % NJ;
    const int b = blk / NJ;
    const long xbase = ((long)b * SS + (long)j * TT) * HH;

    // zero LDS pad regions (s = 300..319) once; guarded by first in-loop barrier
    for (int idx = tid; idx < 20 * KSTR; idx += 512) sK[300 * KSTR + idx] = 0;
    for (int idx = tid; idx < DKV * 32; idx += 512) {
        const int d = idx >> 5, c = 300 + (idx & 31);
        if (c < VSTR) sVT[d * VSTR + c] = 0;
    }

    // q-tile ownership: wave w owns tiles w, w+8, w+16 (<19)
    int myT[MAXTILE]; int nMy = 0;
    for (int t = w; t < NQT; t += NWAVE) myT[nMy++] = t;

    f32x4 y[MAXTILE][4];   // final-output C-frags, accumulated across heads
    #pragma unroll
    for (int a = 0; a < MAXTILE; ++a)
        #pragma unroll
        for (int n = 0; n < 4; ++n) { y[a][n][0]=0.f; y[a][n][1]=0.f; y[a][n][2]=0.f; y[a][n][3]=0.f; }

    for (int h = 0; h < NHEAD; ++h) {
        __syncthreads();   // prior head's readers of sK/sVT/sW* are done

        // ---- stage W^T head slices into LDS (bf16) ----
        for (int idx = tid; idx < 4096; idx += 512) {
            const int d = idx & 63;      // lane-consecutive -> coalesced global reads
            const int i = idx >> 6;
            sWq[d * WSTR + i] = f2bf(Wq[i * HDW + h * DKV + d]);
            sWk[d * WSTR + i] = f2bf(Wk[i * HDW + h * DKV + d]);
            sWv[d * WSTR + i] = f2bf(Wv[i * HDW + h * DKV + d]);
            sWo[d * WSTR + i] = f2bf(Wo[(h * DKV + i) * HH + d]);  // [c][e] = Wo[h*64+e][c]
        }
        __syncthreads();

        // ---- K'/V' projection: 38 tile-jobs round-robin over 8 waves ----
        for (int jb = w; jb < 2 * NQT; jb += NWAVE) {
            const int   isV  = jb >= NQT;
            const int   tile = isV ? jb - NQT : jb;
            const float* X   = isV ? v : k;
            const short* sW  = isV ? sWv : sWk;
            int r = tile * 16 + L15; if (r > TT - 1) r = TT - 1;   // clamp (masked later)
            short8 afr[2];
            #pragma unroll
            for (int kt = 0; kt < 2; ++kt) {
                const float* px = X + xbase + (long)r * HH + kt * 32 + quad * 8;
                const float4 x0 = *(const float4*)px;
                const float4 x1 = *(const float4*)(px + 4);
                short8 a;
                a[0]=f2bf(x0.x); a[1]=f2bf(x0.y); a[2]=f2bf(x0.z); a[3]=f2bf(x0.w);
                a[4]=f2bf(x1.x); a[5]=f2bf(x1.y); a[6]=f2bf(x1.z); a[7]=f2bf(x1.w);
                afr[kt] = a;
            }
            #pragma unroll
            for (int nt = 0; nt < 4; ++nt) {
                f32x4 c; c[0]=0.f; c[1]=0.f; c[2]=0.f; c[3]=0.f;
                #pragma unroll
                for (int kt = 0; kt < 2; ++kt) {
                    const short8 bfr = *(const short8*)&sW[(nt*16 + L15) * WSTR + kt*32 + quad*8];
                    c = MFMA(afr[kt], bfr, c);
                }
                #pragma unroll
                for (int rr = 0; rr < 4; ++rr) {
                    const int s = tile*16 + quad*4 + rr;
                    if (s < TT) {
                        const short bv = f2bf(c[rr]);
                        const int d = nt*16 + L15;
                        if (isV) sVT[d * VSTR + s] = bv;
                        else     sK [s * KSTR + d] = bv;
                    }
                }
            }
        }
        __syncthreads();

        // ---- attention, per wave over its q-tiles ----
        for (int ti = 0; ti < nMy; ++ti) {
            const int tile = myT[ti];

            // Q'-tile projection -> scratch -> A-frags (scale 1/8 folded in)
            short8 qa[2];
            {
                int r = tile * 16 + L15; if (r > TT - 1) r = TT - 1;
                short8 afr[2];
                #pragma unroll
                for (int kt = 0; kt < 2; ++kt) {
                    const float* px = q + xbase + (long)r * HH + kt * 32 + quad * 8;
                    const float4 x0 = *(const float4*)px;
                    const float4 x1 = *(const float4*)(px + 4);
                    short8 a;
                    a[0]=f2bf(x0.x); a[1]=f2bf(x0.y); a[2]=f2bf(x0.z); a[3]=f2bf(x0.w);
                    a[4]=f2bf(x1.x); a[5]=f2bf(x1.y); a[6]=f2bf(x1.z); a[7]=f2bf(x1.w);
                    afr[kt] = a;
                }
                #pragma unroll
                for (int nt = 0; nt < 4; ++nt) {
                    f32x4 c; c[0]=0.f; c[1]=0.f; c[2]=0.f; c[3]=0.f;
                    #pragma unroll
                    for (int kt = 0; kt < 2; ++kt) {
                        const short8 bfr = *(const short8*)&sWq[(nt*16 + L15) * WSTR + kt*32 + quad*8];
                        c = MFMA(afr[kt], bfr, c);
                    }
                    #pragma unroll
                    for (int rr = 0; rr < 4; ++rr)
                        sScr[w][(quad*4+rr)*KSTR + nt*16 + L15] = f2bf(c[rr] * 0.125f);
                }
                LGKM_BAR();
                qa[0] = *(const short8*)&sScr[w][L15*KSTR + quad*8];
                qa[1] = *(const short8*)&sScr[w][L15*KSTR + 32 + quad*8];
            }

            float m[4] = {-3e38f, -3e38f, -3e38f, -3e38f};
            float l[4] = {0.f, 0.f, 0.f, 0.f};
            f32x4 o[4];
            #pragma unroll
            for (int nt = 0; nt < 4; ++nt) { o[nt][0]=0.f; o[nt][1]=0.f; o[nt][2]=0.f; o[nt][3]=0.f; }

            for (int st = 0; st < NST; ++st) {
                // S-tile = Q (16x64) . K'^T (64x32): two col-halves
                f32x4 s0, s1;
                s0[0]=0.f;s0[1]=0.f;s0[2]=0.f;s0[3]=0.f;
                s1[0]=0.f;s1[1]=0.f;s1[2]=0.f;s1[3]=0.f;
                #pragma unroll
                for (int kt = 0; kt < 2; ++kt) {
                    const short8 b0 = *(const short8*)&sK[(st*32      + L15) * KSTR + kt*32 + quad*8];
                    const short8 b1 = *(const short8*)&sK[(st*32 + 16 + L15) * KSTR + kt*32 + quad*8];
                    s0 = MFMA(qa[kt], b0, s0);
                    s1 = MFMA(qa[kt], b1, s1);
                }
                if (st == NST - 1) {   // mask s >= 300
                    if (L15 >= 12) { s0[0]=-1e38f; s0[1]=-1e38f; s0[2]=-1e38f; s0[3]=-1e38f; }
                    s1[0]=-1e38f; s1[1]=-1e38f; s1[2]=-1e38f; s1[3]=-1e38f;
                }
                float corr[4];
                #pragma unroll
                for (int rr = 0; rr < 4; ++rr) {
                    float t = fmaxf(s0[rr], s1[rr]);
                    t = fmaxf(t, __shfl_xor(t, 1));
                    t = fmaxf(t, __shfl_xor(t, 2));
                    t = fmaxf(t, __shfl_xor(t, 4));
                    t = fmaxf(t, __shfl_xor(t, 8));
                    const float mn = fmaxf(m[rr], t);
                    corr[rr] = __expf(m[rr] - mn);
                    m[rr] = mn;
                    const float p0 = __expf(s0[rr] - mn);
                    const float p1 = __expf(s1[rr] - mn);
                    float rs = p0 + p1;
                    rs += __shfl_xor(rs, 1);
                    rs += __shfl_xor(rs, 2);
                    rs += __shfl_xor(rs, 4);
                    rs += __shfl_xor(rs, 8);
                    l[rr] = l[rr] * corr[rr] + rs;
                    sScr[w][(quad*4+rr)*KSTR + L15]      = f2bf(p0);
                    sScr[w][(quad*4+rr)*KSTR + 16 + L15] = f2bf(p1);
                }
                #pragma unroll
                for (int nt = 0; nt < 4; ++nt) {
                    o[nt][0] *= corr[0]; o[nt][1] *= corr[1];
                    o[nt][2] *= corr[2]; o[nt][3] *= corr[3];
                }
                LGKM_BAR();
                const short8 pa = *(const short8*)&sScr[w][L15*KSTR + quad*8];  // P A-frag (16x32)
                #pragma unroll
                for (int nt = 0; nt < 4; ++nt) {
                    const short8 vb = *(const short8*)&sVT[(nt*16 + L15) * VSTR + st*32 + quad*8];
                    o[nt] = MFMA(pa, vb, o[nt]);
                }
            }

            // epilogue: normalize, out-project with Wo_h, accumulate into y
            float linv[4];
            #pragma unroll
            for (int rr = 0; rr < 4; ++rr) linv[rr] = 1.f / l[rr];
            #pragma unroll
            for (int nt = 0; nt < 4; ++nt)
                #pragma unroll
                for (int rr = 0; rr < 4; ++rr)
                    sScr[w][(quad*4+rr)*KSTR + nt*16 + L15] = f2bf(o[nt][rr] * linv[rr]);
            LGKM_BAR();
            const short8 oa0 = *(const short8*)&sScr[w][L15*KSTR + quad*8];
            const short8 oa1 = *(const short8*)&sScr[w][L15*KSTR + 32 + quad*8];
            #pragma unroll
            for (int nt = 0; nt < 4; ++nt) {
                const short8 w0 = *(const short8*)&sWo[(nt*16 + L15) * WSTR + quad*8];
                const short8 w1 = *(const short8*)&sWo[(nt*16 + L15) * WSTR + 32 + quad*8];
                y[ti][nt] = MFMA(oa0, w0, y[ti][nt]);
                y[ti][nt] = MFMA(oa1, w1, y[ti][nt]);
            }
        } // ti
    } // h

    // final coalesced stores (block owns its 300x64 output rows entirely)
    for (int ti = 0; ti < nMy; ++ti) {
        const int tile = myT[ti];
        #pragma unroll
        for (int nt = 0; nt < 4; ++nt)
            #pragma unroll
            for (int rr = 0; rr < 4; ++rr) {
                const int row = tile*16 + quad*4 + rr;
                if (row < TT)
                    out[xbase + (long)row * HH + nt*16 + L15] = y[ti][nt][rr];
            }
    }
}

extern "C" void kernel_launch(void* const* d_in, const int* in_sizes, int n_in,
                              void* d_out, int out_size, void* d_ws, size_t ws_size,
                              hipStream_t stream) {
    const float* q  = (const float*)d_in[0];
    const float* k  = (const float*)d_in[1];
    const float* v  = (const float*)d_in[2];
    const float* Wq = (const float*)d_in[3];
    const float* Wk = (const float*)d_in[4];
    const float* Wv = (const float*)d_in[5];
    const float* Wo = (const float*)d_in[6];
    float* out = (float*)d_out;

    const dim3 grid(NB * NJ);   // 400 blocks, one per (b, j); output fully overwritten
    mha_mfma<<<grid, 512, 0, stream>>>(q, k, v, Wq, Wk, Wv, Wo, out);
}